// Round 3
// baseline (556.067 us; speedup 1.0000x reference)
//
#include <hip/hip_runtime.h>
#include <hip/hip_bf16.h>
#include <math.h>

#define NTOK 8192
#define DDIM 256
#define KCB  4096
#define TM   32
#define KSPL 4
#define KBLK (KCB / KSPL)   // 1024
#define KC   64
#define DC   64
#define GEPS 1e-10f

// ws layout (float units), total 81921 floats (~328 KB)
#define WS_ESQ   0
#define WS_ZSQ   (WS_ESQ + KCB)          // 4096
#define WS_PVAL  (WS_ZSQ + NTOK)         // 12288
#define WS_PIDX  (WS_PVAL + NTOK*KSPL)   // 45056
#define WS_HIST  (WS_PIDX + NTOK*KSPL)   // 77824
#define WS_COMM  (WS_HIST + KCB)         // 81920

// out offsets (FLOAT32 elements): z_q, embedding, indices, commitment, perplexity, entropy
#define OUT_ZQ   0
#define OUT_EMB  (NTOK * DDIM)             // 2097152
#define OUT_IDX  (2 * NTOK * DDIM)         // 4194304
#define OUT_SCAL (2 * NTOK * DDIM + NTOK)  // 4202496

// ---------------- prep: e_sq[k], z_sq[tok], zero hist/comm ----------------
__global__ __launch_bounds__(256) void k_prep(const float* __restrict__ cb,
                                              const float* __restrict__ z,
                                              float* __restrict__ esq,
                                              float* __restrict__ zsq,
                                              float* __restrict__ hist,
                                              float* __restrict__ comm) {
  const int lane = threadIdx.x & 63;
  const int wv   = threadIdx.x >> 6;
  const int row  = blockIdx.x * 4 + wv;   // 0 .. 12287 (4096 cb rows + 8192 z rows)
  const float* src = (row < KCB) ? (cb + (size_t)row * DDIM)
                                 : (z  + (size_t)(row - KCB) * DDIM);
  float4 v = *(const float4*)(src + 4 * lane);
  float s = v.x * v.x + v.y * v.y + v.z * v.z + v.w * v.w;
  #pragma unroll
  for (int o = 32; o > 0; o >>= 1) s += __shfl_down(s, o);
  if (lane == 0) {
    if (row < KCB) esq[row] = s;
    else           zsq[row - KCB] = s;
  }
  const int gid = blockIdx.x * 256 + threadIdx.x;
  if (gid < KCB) hist[gid] = 0.0f;
  if (gid == KCB) comm[0] = 0.0f;
}

// ---------------- fused distance-GEMM + gumbel + partial argmax ----------------
// grid (NTOK/TM, KSPL) = (256,4), block 256. 32 tokens x 1024-k slice per block.
__global__ __launch_bounds__(256) void k_score(const float* __restrict__ z,
                                               const float* __restrict__ u,
                                               const float* __restrict__ cb,
                                               const float* __restrict__ esq,
                                               const float* __restrict__ zsq,
                                               float* __restrict__ pval,
                                               int* __restrict__ pidx) {
  __shared__ float zsm[DDIM][TM + 2];   // z tile transposed [d][t]
  __shared__ float csm[DC][KC + 4];     // codebook chunk transposed [d][k]

  const int tid  = threadIdx.x;
  const int tok0 = blockIdx.x * TM;
  const int kb   = blockIdx.y * KBLK;

  #pragma unroll
  for (int j = 0; j < 8; ++j) {
    const int e4 = tid + 256 * j;
    const int t  = e4 >> 6;
    const int d  = (e4 & 63) << 2;
    float4 v = *(const float4*)(z + (size_t)(tok0 + t) * DDIM + d);
    zsm[d + 0][t] = v.x; zsm[d + 1][t] = v.y;
    zsm[d + 2][t] = v.z; zsm[d + 3][t] = v.w;
  }

  const int tx = tid & 15;
  const int ty = tid >> 4;
  const int t0 = 2 * ty, t1 = t0 + 1;

  float bv0 = -3.402823e38f, bv1 = -3.402823e38f;
  int   bi0 = 0, bi1 = 0;

  const float zq0 = zsq[tok0 + t0];
  const float zq1 = zsq[tok0 + t1];

  for (int kc = 0; kc < KBLK / KC; ++kc) {
    const int k0 = kb + kc * KC;
    float acc[2][4] = {{0.f,0.f,0.f,0.f},{0.f,0.f,0.f,0.f}};

    for (int dc = 0; dc < DDIM / DC; ++dc) {
      const int d0 = dc * DC;
      __syncthreads();
      #pragma unroll
      for (int j = 0; j < 4; ++j) {
        const int e4 = tid + 256 * j;
        const int kk = e4 >> 4;
        const int dd = (e4 & 15) << 2;
        float4 v = *(const float4*)(cb + (size_t)(k0 + kk) * DDIM + d0 + dd);
        csm[dd + 0][kk] = v.x; csm[dd + 1][kk] = v.y;
        csm[dd + 2][kk] = v.z; csm[dd + 3][kk] = v.w;
      }
      __syncthreads();

      float ck[2][4] = {{0.f,0.f,0.f,0.f},{0.f,0.f,0.f,0.f}};
      #pragma unroll
      for (int d = 0; d < DC; ++d) {
        const float2 zz = *(const float2*)&zsm[d0 + d][t0];
        const float4 cc = *(const float4*)&csm[d][4 * tx];
        ck[0][0] += zz.x * cc.x; ck[0][1] += zz.x * cc.y;
        ck[0][2] += zz.x * cc.z; ck[0][3] += zz.x * cc.w;
        ck[1][0] += zz.y * cc.x; ck[1][1] += zz.y * cc.y;
        ck[1][2] += zz.y * cc.z; ck[1][3] += zz.y * cc.w;
      }
      #pragma unroll
      for (int i = 0; i < 2; ++i)
        #pragma unroll
        for (int jj = 0; jj < 4; ++jj) acc[i][jj] += ck[i][jj];
    }

    // score = -((z_sq + e_sq) - 2*dot) + gumbel   (matches ref op order, tau=1)
    const int kg = k0 + 4 * tx;
    const float4 es = *(const float4*)(esq + kg);
    const float4 u0 = *(const float4*)(u + (size_t)(tok0 + t0) * KCB + kg);
    const float4 u1 = *(const float4*)(u + (size_t)(tok0 + t1) * KCB + kg);
    const float esa[4] = {es.x, es.y, es.z, es.w};
    const float u0a[4] = {u0.x, u0.y, u0.z, u0.w};
    const float u1a[4] = {u1.x, u1.y, u1.z, u1.w};
    #pragma unroll
    for (int jj = 0; jj < 4; ++jj) {
      const float g0 = -logf(-logf(u0a[jj] + GEPS) + GEPS);
      const float g1 = -logf(-logf(u1a[jj] + GEPS) + GEPS);
      const float s0 = -((zq0 + esa[jj]) - 2.0f * acc[0][jj]) + g0;
      const float s1 = -((zq1 + esa[jj]) - 2.0f * acc[1][jj]) + g1;
      if (s0 > bv0) { bv0 = s0; bi0 = kg + jj; }
      if (s1 > bv1) { bv1 = s1; bi1 = kg + jj; }
    }
  }

  // block argmax across tx groups (overlay on csm after all reads done)
  __syncthreads();
  float* bvp = (float*)&csm[0][0];
  int*   bip = (int*)&csm[0][0] + TM * 16;
  bvp[t0 * 16 + tx] = bv0; bip[t0 * 16 + tx] = bi0;
  bvp[t1 * 16 + tx] = bv1; bip[t1 * 16 + tx] = bi1;
  __syncthreads();
  if (tid < TM) {
    float best = bvp[tid * 16];
    int  besti = bip[tid * 16];
    for (int x = 1; x < 16; ++x) {          // ascending tx = ascending k; strict > keeps first
      const float v = bvp[tid * 16 + x];
      if (v > best) { best = v; besti = bip[tid * 16 + x]; }
    }
    pval[(size_t)(tok0 + tid) * KSPL + blockIdx.y] = best;
    pidx[(size_t)(tok0 + tid) * KSPL + blockIdx.y] = besti;
  }
}

// ---------------- finalize per token: merge splits, gather, outputs (f32) ----------------
__global__ __launch_bounds__(256) void k_final(const float* __restrict__ z,
                                               const float* __restrict__ cb,
                                               const float* __restrict__ pval,
                                               const int* __restrict__ pidx,
                                               float* __restrict__ out,
                                               float* __restrict__ hist,
                                               float* __restrict__ comm) {
  const int lane = threadIdx.x & 63;
  const int wv   = threadIdx.x >> 6;
  const int tok  = blockIdx.x * 4 + wv;

  float bv = pval[(size_t)tok * KSPL];
  int   bi = pidx[(size_t)tok * KSPL];
  #pragma unroll
  for (int s = 1; s < KSPL; ++s) {          // ascending split = ascending k
    const float v = pval[(size_t)tok * KSPL + s];
    if (v > bv) { bv = v; bi = pidx[(size_t)tok * KSPL + s]; }
  }
  bi = min(max(bi, 0), KCB - 1);

  const float4 c  = *(const float4*)(cb + (size_t)bi * DDIM + 4 * lane);
  const float4 zv = *(const float4*)(z + (size_t)tok * DDIM + 4 * lane);
  // z_q = z + (quantized - z) in f32 (== quantized exactly)
  float4 q;
  q.x = zv.x + (c.x - zv.x);
  q.y = zv.y + (c.y - zv.y);
  q.z = zv.z + (c.z - zv.z);
  q.w = zv.w + (c.w - zv.w);

  const size_t o = (size_t)tok * DDIM + 4 * lane;
  *(float4*)(out + OUT_ZQ  + o) = q;
  *(float4*)(out + OUT_EMB + o) = c;

  const float dx = q.x - zv.x, dy = q.y - zv.y, dz = q.z - zv.z, dw = q.w - zv.w;
  float s = dx * dx + dy * dy + dz * dz + dw * dw;
  #pragma unroll
  for (int o2 = 32; o2 > 0; o2 >>= 1) s += __shfl_down(s, o2);
  if (lane == 0) {
    atomicAdd(comm, s);
    atomicAdd(&hist[bi], 1.0f);
    out[OUT_IDX + tok] = (float)bi;
  }
}

// ---------------- scalars: usage EMA -> entropy/perplexity, commitment mean ----------------
__global__ __launch_bounds__(1024) void k_scal(const float* __restrict__ cu,
                                               const float* __restrict__ hist,
                                               const float* __restrict__ comm,
                                               float* __restrict__ out) {
  __shared__ float red[1024];
  const int tid = threadIdx.x;
  float us[4];
  float s = 0.0f;
  #pragma unroll
  for (int j = 0; j < 4; ++j) {
    const int k = tid * 4 + j;
    us[j] = cu[k] * 0.99f + hist[k];
    s += us[j];
  }
  red[tid] = s; __syncthreads();
  for (int o = 512; o > 0; o >>= 1) {
    if (tid < o) red[tid] += red[tid + o];
    __syncthreads();
  }
  const float usum = red[0];
  __syncthreads();
  float e = 0.0f;
  #pragma unroll
  for (int j = 0; j < 4; ++j) {
    const float p = (usum > 0.0f) ? (us[j] / (usum + GEPS)) : (1.0f / (float)KCB);
    e -= p * logf(p + GEPS);
  }
  red[tid] = e; __syncthreads();
  for (int o = 512; o > 0; o >>= 1) {
    if (tid < o) red[tid] += red[tid + o];
    __syncthreads();
  }
  if (tid == 0) {
    const float entropy = red[0];
    out[OUT_SCAL + 0] = comm[0] / (float)((size_t)NTOK * DDIM);
    out[OUT_SCAL + 1] = expf(entropy);
    out[OUT_SCAL + 2] = entropy;
  }
}

extern "C" void kernel_launch(void* const* d_in, const int* in_sizes, int n_in,
                              void* d_out, int out_size, void* d_ws, size_t ws_size,
                              hipStream_t stream) {
  const float* z  = (const float*)d_in[0];
  const float* u  = (const float*)d_in[1];
  const float* cb = (const float*)d_in[2];
  const float* cu = (const float*)d_in[3];

  float* ws   = (float*)d_ws;
  float* esq  = ws + WS_ESQ;
  float* zsq  = ws + WS_ZSQ;
  float* pv   = ws + WS_PVAL;
  int*   pi   = (int*)(ws + WS_PIDX);
  float* hist = ws + WS_HIST;
  float* comm = ws + WS_COMM;
  float* out  = (float*)d_out;

  k_prep <<<dim3((KCB + NTOK) / 4), dim3(256), 0, stream>>>(cb, z, esq, zsq, hist, comm);
  k_score<<<dim3(NTOK / TM, KSPL), dim3(256), 0, stream>>>(z, u, cb, esq, zsq, pv, pi);
  k_final<<<dim3(NTOK / 4), dim3(256), 0, stream>>>(z, cb, pv, pi, out, hist, comm);
  k_scal <<<dim3(1), dim3(1024), 0, stream>>>(cu, hist, comm, out);
}